// Round 12
// baseline (1000.755 us; speedup 1.0000x reference)
//
#include <hip/hip_runtime.h>
#include <hip/hip_bf16.h>

typedef __hip_bfloat16 bf16;
typedef __bf16 bf16x8 __attribute__((ext_vector_type(8)));
typedef float f32x4  __attribute__((ext_vector_type(4)));

#define NBATCH 8
#define LTOK   576
#define NT     4608
#define CW     768
#define NH     12
#define HDIM   64
#define DEPTH  4
#define MLPW   3072
#define GRIDP  24
#define IMGS   384
#define QKVW   2304

static __device__ __forceinline__ unsigned bfpair(float a, float b){
    bf16 x = __float2bfloat16(a), y = __float2bfloat16(b);
    return ((unsigned)*(unsigned short*)&y << 16) | *(unsigned short*)&x;
}
static __device__ __forceinline__ float b2f(bf16 v){ return __bfloat162float(v); }

// bijective XCD-aware remap (m204) — row-major chunks
static __device__ __forceinline__ int xcd_swizzle(int orig, int nwg){
    int q = nwg >> 3, r = nwg & 7;
    int xcd = orig & 7, j = orig >> 3;
    int base = (xcd < r) ? xcd*(q+1) : r*(q+1) + (xcd-r)*q;
    return base + j;
}

// async global -> LDS, 16B per lane; LDS dest = wave-uniform base + lane*16
static __device__ __forceinline__ void gl_lds16(const bf16* g, bf16* l){
    __builtin_amdgcn_global_load_lds(
        (const __attribute__((address_space(1))) unsigned int*)(const void*)g,
        (__attribute__((address_space(3))) unsigned int*)(void*)l, 16, 0, 0);
}

// ---------------- RoPE cache ----------------
__global__ void rope_cache_kernel(float* __restrict__ rc){
    int idx = blockIdx.x*256 + threadIdx.x;
    if (idx >= LTOK*16) return;
    int l = idx >> 4, f = idx & 15;
    int py = l / GRIDP, px = l % GRIDP;
    float u = (px + 0.5f) / (float)GRIDP;
    float v = (py + 0.5f) / (float)GRIDP;
    float fr = (float)f / (15.0f + 1e-9f);
    float inv = expf(-fr * 9.210340371976184f);
    float sx, cx, sy, cy;
    sincosf(u * inv, &sx, &cx);
    sincosf(v * inv, &sy, &cy);
    rc[idx]         = cx;
    rc[idx + 9216]  = sx;
    rc[idx + 18432] = cy;
    rc[idx + 27648] = sy;
}

// ---------------- patch gather ----------------
__global__ void patch_gather(const float* __restrict__ img, bf16* __restrict__ p){
    int idx = blockIdx.x*256 + threadIdx.x;
    int t = idx / CW, kk = idx % CW;
    int n = t / LTOK, l = t % LTOK;
    int py = l / GRIDP, px = l % GRIDP;
    int i = kk / 48, r = kk % 48, j = r / 3, c = r % 3;
    p[idx] = __float2bfloat16(img[((size_t)(n*IMGS + py*16 + i)*IMGS + px*16 + j)*3 + c]);
}

// ---------------- batched weight transpose+convert: f32 [K][N] -> bf16 [N][K]
__global__ __launch_bounds__(256) void wtrans_b(const float* __restrict__ in, bf16* __restrict__ out,
                                                int K, int N, size_t inStride, size_t outStride){
    in  += blockIdx.z * inStride;
    out += blockIdx.z * outStride;
    __shared__ float t[32][33];
    const int n0 = blockIdx.x*32, k0 = blockIdx.y*32;
    const int tx = threadIdx.x & 31, ty = threadIdx.x >> 5;
    #pragma unroll
    for (int r = 0; r < 4; ++r)
        t[ty + 8*r][tx] = in[(size_t)(k0 + ty + 8*r)*N + n0 + tx];
    __syncthreads();
    #pragma unroll
    for (int r = 0; r < 4; ++r)
        out[(size_t)(n0 + ty + 8*r)*K + k0 + tx] = __float2bfloat16(t[tx][ty + 8*r]);
}

// ---------------- pack qkv biases ----------------
__global__ void bias_pack(const float* __restrict__ bq, const float* __restrict__ bk,
                          const float* __restrict__ bv, float* __restrict__ o){
    int idx = blockIdx.x*256 + threadIdx.x;    // 4*2304
    int l = idx / QKVW, r = idx % QKVW;
    const float* src = (r < 768) ? (bq + l*768 + r) :
                       (r < 1536) ? (bk + l*768 + r - 768) : (bv + l*768 + r - 1536);
    o[idx] = *src;
}

// fast tanh-gelu: tanh via hardware v_exp_f32 (vs ~25-op libm tanhf)
static __device__ __forceinline__ float gelu_tanh(float x){
    float a = 0.7978845608028654f*(x + 0.044715f*x*x*x);
    float e = __expf(-2.0f*fabsf(a));
    float th = (1.0f - e) / (1.0f + e);
    th = copysignf(th, a);
    return 0.5f*x*(1.0f + th);
}

// ---------------- MFMA GEMM 128x64, BK=64, NBUF-deep async LDS pipeline with
// COUNTED vmcnt (T4). NBUF=2: R3 structure (best for high-block-count grids).
// NBUF=3: prefetch 2 steps ahead (~1000cy slack) for latency-bound narrow
// grids (432 blocks, 1.7/CU — 72KB LDS capacity cap of 2/CU is free there).
// XCD mapping: wide grids (>=24 col-tiles) use a 2x4 rectangular per-XCD
// chunk; narrow grids row-major chunks. LDS row pitch 64 bf16; chunk c of
// row r at position c^(r&7) (swizzle via permuted GLOBAL source address).
// EPI: 0 = bf16 store, 1 = fp32 residual add, 2 = bf16 gelu, 3 = fp32 store
template<int EPI, int NBUF, typename TC>
__global__ __launch_bounds__(256) void gemm_a(const bf16* __restrict__ A, int lda,
                                              const bf16* __restrict__ B, int ldb,
                                              const float* __restrict__ bias,
                                              TC* __restrict__ C, int ldc, int K){
    __shared__ bf16 As[NBUF][128*64];
    __shared__ bf16 Bs[NBUF][64*64];
    const int tid = threadIdx.x;
    const int w = tid >> 6, l = tid & 63;
    const int quad = l >> 4, lr = l & 15;
    const int wm = w & 1, wn = w >> 1;

    const int gx = gridDim.x, gy = gridDim.y;
    const int orig = blockIdx.y * gx + blockIdx.x;
    int tx, ty;
    if (gx >= 24 && (gx & 1) == 0 && (gy & 3) == 0){
        const int cw = gx >> 1, ch = gy >> 2;
        const int xcd = orig & 7, j = orig >> 3;
        const int lx = j % cw, ly = j / cw;
        tx = (xcd & 1)*cw + lx;
        ty = (xcd >> 1)*ch + ly;
    } else {
        const int swz = xcd_swizzle(orig, gx*gy);
        tx = swz % gx; ty = swz / gx;
    }
    const int rowT = ty * 128;
    const int colT = tx * 64;

    const int srow = l >> 3;
    const int schk = (l & 7) ^ (srow & 7);

    const bf16* Ap[4];
    const bf16* Bp[2];
    #pragma unroll
    for (int t = 0; t < 4; ++t)
        Ap[t] = A + (size_t)(rowT + (w*4+t)*8 + srow)*lda + schk*8;
    #pragma unroll
    for (int t = 0; t < 2; ++t)
        Bp[t] = B + (size_t)(colT + (w*2+t)*8 + srow)*ldb + schk*8;

    auto STAGE = [&](int k0, int buf){
        #pragma unroll
        for (int t = 0; t < 4; ++t) gl_lds16(Ap[t] + k0, &As[buf][(w*4+t)*512]);
        #pragma unroll
        for (int t = 0; t < 2; ++t) gl_lds16(Bp[t] + k0, &Bs[buf][(w*2+t)*512]);
    };

    f32x4 acc[4][2];
    #pragma unroll
    for (int i = 0; i < 4; ++i)
        #pragma unroll
        for (int j = 0; j < 2; ++j) acc[i][j] = (f32x4){0.f,0.f,0.f,0.f};

    const int S = K >> 6;
    #pragma unroll
    for (int b = 0; b < NBUF; ++b)
        if (b < S) STAGE(b*64, b);

    int cur = 0;
    for (int s = 0; s < S; ++s){
        const int left = S - 1 - s;          // stages still in flight beyond cur
        if (NBUF == 3){
            if      (left >= 2) asm volatile("s_waitcnt vmcnt(12)" ::: "memory");
            else if (left == 1) asm volatile("s_waitcnt vmcnt(6)"  ::: "memory");
            else                asm volatile("s_waitcnt vmcnt(0)"  ::: "memory");
        } else {
            if      (left >= 1) asm volatile("s_waitcnt vmcnt(6)"  ::: "memory");
            else                asm volatile("s_waitcnt vmcnt(0)"  ::: "memory");
        }
        __builtin_amdgcn_s_barrier();
        #pragma unroll
        for (int kh = 0; kh < 2; ++kh){
            bf16x8 af[4], bfr[2];
            #pragma unroll
            for (int i = 0; i < 4; ++i){
                int r = wm*64 + i*16 + lr;
                af[i] = *(const bf16x8*)(&As[cur][r*64 + (((kh*4 + quad) ^ (r & 7))*8)]);
            }
            #pragma unroll
            for (int j = 0; j < 2; ++j){
                int r = wn*32 + j*16 + lr;
                bfr[j] = *(const bf16x8*)(&Bs[cur][r*64 + (((kh*4 + quad) ^ (r & 7))*8)]);
            }
            #pragma unroll
            for (int i = 0; i < 4; ++i)
                #pragma unroll
                for (int j = 0; j < 2; ++j)
                    acc[i][j] = __builtin_amdgcn_mfma_f32_16x16x32_bf16(af[i], bfr[j], acc[i][j], 0, 0, 0);
        }
        __builtin_amdgcn_s_barrier();
        if (s + NBUF < S) STAGE((s + NBUF)*64, cur);
        cur = (cur + 1 == NBUF) ? 0 : cur + 1;
    }

    #pragma unroll
    for (int i = 0; i < 4; ++i){
        #pragma unroll
        for (int j = 0; j < 2; ++j){
            const int row = rowT + wm*64 + i*16 + quad*4;
            const int col = colT + wn*32 + j*16 + lr;
            const float bb = bias ? bias[col] : 0.f;
            #pragma unroll
            for (int r = 0; r < 4; ++r){
                float val = acc[i][j][r] + bb;
                TC* cp = C + (size_t)(row + r)*ldc + col;
                if (EPI == 2) val = gelu_tanh(val);
                if (EPI == 1) val += *(float*)cp;
                if (EPI == 0 || EPI == 2) *(bf16*)cp = __float2bfloat16(val);
                else                      *(float*)cp = val;
            }
        }
    }
}

// ---------------- LayerNorm: wave per token ----------------
__global__ __launch_bounds__(256) void ln_wave(const float* __restrict__ x,
                                               const float* __restrict__ sc,
                                               const float* __restrict__ bs,
                                               bf16* __restrict__ y){
    const int tid = threadIdx.x, w = tid >> 6, l = tid & 63;
    const int t = blockIdx.x*4 + w;
    const float4* xr = (const float4*)(x + (size_t)t*CW);
    float4 a[3];
    #pragma unroll
    for (int i = 0; i < 3; ++i) a[i] = xr[l + 64*i];
    float s = 0.f;
    #pragma unroll
    for (int i = 0; i < 3; ++i) s += a[i].x + a[i].y + a[i].z + a[i].w;
    #pragma unroll
    for (int off = 1; off < 64; off <<= 1) s += __shfl_xor(s, off);
    const float m = s * (1.0f/768.0f);
    float vs = 0.f;
    #pragma unroll
    for (int i = 0; i < 3; ++i){
        float dx = a[i].x-m, dy = a[i].y-m, dz = a[i].z-m, dw = a[i].w-m;
        vs += dx*dx + dy*dy + dz*dz + dw*dw;
    }
    #pragma unroll
    for (int off = 1; off < 64; off <<= 1) vs += __shfl_xor(vs, off);
    const float rs = rsqrtf(vs*(1.0f/768.0f) + 1e-6f);
    const float4* scp = (const float4*)sc;
    const float4* bsp = (const float4*)bs;
    uint2* yr = (uint2*)(y + (size_t)t*CW);
    #pragma unroll
    for (int i = 0; i < 3; ++i){
        float4 sv = scp[l + 64*i], bv = bsp[l + 64*i];
        float r0 = (a[i].x-m)*rs*sv.x + bv.x;
        float r1 = (a[i].y-m)*rs*sv.y + bv.y;
        float r2 = (a[i].z-m)*rs*sv.z + bv.z;
        float r3 = (a[i].w-m)*rs*sv.w + bv.w;
        yr[l + 64*i] = make_uint2(bfpair(r0,r1), bfpair(r2,r3));
    }
}

// ---------------- RoPE apply on q and k inside packed qkv ----------------
__global__ void rope_qk(bf16* __restrict__ qkv, const float* __restrict__ rc){
    int idx = blockIdx.x*256 + threadIdx.x;   // NT*768 pairs
    int tok = idx / 768;
    int r = idx % 768;
    int rr, base;
    if (r < 384){ base = 0; rr = r; } else { base = 768; rr = r - 384; }
    int hh = rr >> 5, p = rr & 31;
    int l = tok % LTOK;
    float c, s;
    if (p < 16){ c = rc[l*16 + p];            s = rc[9216 + l*16 + p]; }
    else       { c = rc[18432 + l*16 + p-16]; s = rc[27648 + l*16 + p-16]; }
    bf16* pp = qkv + (size_t)tok*QKVW + base + hh*64 + 2*p;
    unsigned u = *(unsigned*)pp;
    bf16 lo = *(bf16*)&u; unsigned short hi16 = u >> 16; bf16 hi = *(bf16*)&hi16;
    float x = b2f(lo), y = b2f(hi);
    *(unsigned*)pp = bfpair(x*c - y*s, x*s + y*c);
}

// ---------------- V transpose ----------------
__global__ __launch_bounds__(256) void vtrans(const bf16* __restrict__ qkv, bf16* __restrict__ vT){
    __shared__ bf16 tile[64][72];
    const int t0 = blockIdx.x*64, hI = blockIdx.y, nI = blockIdx.z;
    const size_t base = ((size_t)nI*LTOK + t0)*QKVW + 1536 + hI*64;
    const int tid = threadIdx.x;
    #pragma unroll
    for (int i = 0; i < 2; ++i){
        int g = i*256 + tid, r = g >> 3, c = g & 7;
        *(uint4*)&tile[r][c*8] = *(const uint4*)(qkv + base + (size_t)r*QKVW + c*8);
    }
    __syncthreads();
    const size_t obase = ((size_t)(nI*NH + hI)*64)*576 + t0;
    #pragma unroll
    for (int i = 0; i < 2; ++i){
        int g = i*256 + tid, d = g >> 3, c = g & 7;
        bf16 tmp[8];
        #pragma unroll
        for (int j = 0; j < 8; ++j) tmp[j] = tile[c*8 + j][d];
        *(uint4*)(vT + obase + (size_t)d*576 + c*8) = *(uint4*)tmp;
    }
}

// ---------------- Flash attention ----------------
__global__ __launch_bounds__(256) void attn_flash(const bf16* __restrict__ qkv,
                                                  const bf16* __restrict__ vT,
                                                  bf16* __restrict__ o){
    __shared__ bf16 Ks[64*72];
    __shared__ bf16 Vs[64*72];
    __shared__ bf16 Ps[64*72];
    __shared__ float alph[64];
    __shared__ float lsum[64];
    const int tid = threadIdx.x;
    const int w = tid >> 6, l = tid & 63;
    const int quad = l >> 4, lr = l & 15;

    const int nwg = gridDim.x * gridDim.y * gridDim.z;
    const int orig = (blockIdx.z * gridDim.y + blockIdx.y) * gridDim.x + blockIdx.x;
    const int swz = xcd_swizzle(orig, nwg);
    const int q0 = (swz % gridDim.x) * 64;
    const int t2 = swz / gridDim.x;
    const int hI = t2 % gridDim.y;
    const int nI = t2 / gridDim.y;

    const size_t tokBase = (size_t)nI * LTOK;
    const int off = hI * 64;
    const size_t vbase = ((size_t)(nI*NH + hI)*64)*576;

    bf16x8 qf[2];
    #pragma unroll
    for (int kh = 0; kh < 2; ++kh)
        qf[kh] = *(const bf16x8*)(qkv + (tokBase + q0 + w*16 + lr)*QKVW + off + kh*32 + quad*8);

    f32x4 oacc[4];
    #pragma unroll
    for (int j = 0; j < 4; ++j) oacc[j] = (f32x4){0.f,0.f,0.f,0.f};
    float m_run = -3.0e38f, l_run = 0.f;

    for (int ch = 0; ch < 9; ++ch){
        __syncthreads();
        #pragma unroll
        for (int i = 0; i < 2; ++i){
            int g = i*256 + tid, r = g >> 3, c = g & 7;
            *(uint4*)(Ks + r*72 + c*8) =
                *(const uint4*)(qkv + (tokBase + ch*64 + r)*QKVW + 768 + off + c*8);
        }
        #pragma unroll
        for (int i = 0; i < 2; ++i){
            int g = i*256 + tid, d = g >> 3, c = g & 7;
            *(uint4*)(Vs + d*72 + c*8) = *(const uint4*)(vT + vbase + (size_t)d*576 + ch*64 + c*8);
        }
        __syncthreads();

        f32x4 st[4];
        #pragma unroll
        for (int t = 0; t < 4; ++t){
            st[t] = (f32x4){0.f,0.f,0.f,0.f};
            #pragma unroll
            for (int kh = 0; kh < 2; ++kh){
                bf16x8 kf = *(const bf16x8*)(Ks + (t*16 + lr)*72 + kh*32 + quad*8);
                st[t] = __builtin_amdgcn_mfma_f32_16x16x32_bf16(kf, qf[kh], st[t], 0, 0, 0);
            }
        }
        float lm = -3.0e38f;
        #pragma unroll
        for (int t = 0; t < 4; ++t)
            #pragma unroll
            for (int r = 0; r < 4; ++r){
                st[t][r] *= 0.125f;
                lm = fmaxf(lm, st[t][r]);
            }
        lm = fmaxf(lm, __shfl_xor(lm, 16));
        lm = fmaxf(lm, __shfl_xor(lm, 32));
        float mn = fmaxf(m_run, lm);
        float alpha = __expf(m_run - mn);
        m_run = mn;
        float ls = 0.f;
        #pragma unroll
        for (int t = 0; t < 4; ++t)
            #pragma unroll
            for (int r = 0; r < 4; ++r){
                float p = __expf(st[t][r] - mn);
                st[t][r] = p; ls += p;
            }
        ls += __shfl_xor(ls, 16);
        ls += __shfl_xor(ls, 32);
        l_run = l_run*alpha + ls;
        if ((tid & 48) == 0) alph[w*16 + lr] = alpha;
        #pragma unroll
        for (int t = 0; t < 4; ++t)
            #pragma unroll
            for (int r = 0; r < 4; ++r)
                Ps[(w*16 + lr)*72 + t*16 + quad*4 + r] = __float2bfloat16(st[t][r]);
        float af[4];
        #pragma unroll
        for (int r = 0; r < 4; ++r) af[r] = alph[w*16 + quad*4 + r];
        #pragma unroll
        for (int j = 0; j < 4; ++j)
            #pragma unroll
            for (int r = 0; r < 4; ++r) oacc[j][r] *= af[r];
        #pragma unroll
        for (int kh = 0; kh < 2; ++kh){
            bf16x8 pf = *(const bf16x8*)(Ps + (w*16 + lr)*72 + kh*32 + quad*8);
            #pragma unroll
            for (int j = 0; j < 4; ++j){
                bf16x8 vf = *(const bf16x8*)(Vs + (j*16 + lr)*72 + kh*32 + quad*8);
                oacc[j] = __builtin_amdgcn_mfma_f32_16x16x32_bf16(pf, vf, oacc[j], 0, 0, 0);
            }
        }
    }

    if ((tid & 48) == 0) lsum[w*16 + lr] = l_run;
    float linv[4];
    #pragma unroll
    for (int r = 0; r < 4; ++r) linv[r] = 1.0f / lsum[w*16 + quad*4 + r];
    #pragma unroll
    for (int j = 0; j < 4; ++j)
        #pragma unroll
        for (int r = 0; r < 4; ++r)
            o[(tokBase + q0 + w*16 + quad*4 + r)*CW + off + j*16 + lr] =
                __float2bfloat16(oacc[j][r] * linv[r]);
}

// ---------------- final mean ----------------
__global__ void mean_kernel(const bf16* __restrict__ y, float* __restrict__ out){
    int c = blockIdx.x*256 + threadIdx.x;
    int n = blockIdx.y;
    float s = 0.f;
    for (int l = 0; l < LTOK; ++l) s += b2f(y[((size_t)n*LTOK + l)*CW + c]);
    out[n*CW + c] = s * (1.0f/576.0f);
}

extern "C" void kernel_launch(void* const* d_in, const int* in_sizes, int n_in,
                              void* d_out, int out_size, void* d_ws, size_t ws_size,
                              hipStream_t stream){
    const float* image = (const float*)d_in[0];
    const float* convk = (const float*)d_in[1];
    const float* convb = (const float*)d_in[2];
    const float* ln1s  = (const float*)d_in[3];
    const float* ln1b  = (const float*)d_in[4];
    const float* wq    = (const float*)d_in[5];
    const float* bq    = (const float*)d_in[6];
    const float* wk    = (const float*)d_in[7];
    const float* bk    = (const float*)d_in[8];
    const float* wv    = (const float*)d_in[9];
    const float* bv    = (const float*)d_in[10];
    const float* wo    = (const float*)d_in[11];
    const float* bo    = (const float*)d_in[12];
    const float* ln2s  = (const float*)d_in[13];
    const float* ln2b  = (const float*)d_in[14];
    const float* w1    = (const float*)d_in[15];
    const float* b1    = (const float*)d_in[16];
    const float* w2    = (const float*)d_in[17];
    const float* b2    = (const float*)d_in[18];
    const float* lnfs  = (const float*)d_in[19];
    const float* lnfb  = (const float*)d_in[20];
    float* out = (float*)d_out;

    const size_t u = (size_t)NT*CW;
    float* ws    = (float*)d_ws;
    float* ropeC = ws;
    float* bqkvA = ws + 36864;
    float* x     = bqkvA + 4*QKVW;
    bf16*  y     = (bf16*)(x + u);
    bf16*  qkv   = y + u;
    bf16*  o     = qkv + (size_t)NT*QKVW;
    bf16*  h     = o + u;
    bf16*  vT    = h + (size_t)NT*MLPW;
    bf16*  convT = vT + u;
    bf16*  wqkvT = convT + 589824;
    bf16*  woT   = wqkvT + (size_t)4*QKVW*CW;
    bf16*  w1T   = woT + (size_t)4*CW*CW;
    bf16*  w2T   = w1T + (size_t)4*CW*MLPW;

    rope_cache_kernel<<<36, 256, 0, stream>>>(ropeC);
    patch_gather<<<(NT*CW)/256, 256, 0, stream>>>(image, y);
    bias_pack<<<36, 256, 0, stream>>>(bq, bk, bv, bqkvA);
    wtrans_b<<<dim3(24,24,1), 256, 0, stream>>>(convk, convT, CW, CW, 0, 0);
    wtrans_b<<<dim3(24,24,4), 256, 0, stream>>>(wq, wqkvT,           CW, CW, (size_t)CW*CW, (size_t)QKVW*CW);
    wtrans_b<<<dim3(24,24,4), 256, 0, stream>>>(wk, wqkvT + 589824,  CW, CW, (size_t)CW*CW, (size_t)QKVW*CW);
    wtrans_b<<<dim3(24,24,4), 256, 0, stream>>>(wv, wqkvT + 1179648, CW, CW, (size_t)CW*CW, (size_t)QKVW*CW);
    wtrans_b<<<dim3(24,24,4), 256, 0, stream>>>(wo, woT,             CW, CW, (size_t)CW*CW, (size_t)CW*CW);
    wtrans_b<<<dim3(96,24,4), 256, 0, stream>>>(w1, w1T,  CW, MLPW, (size_t)CW*MLPW, (size_t)CW*MLPW);
    wtrans_b<<<dim3(24,96,4), 256, 0, stream>>>(w2, w2T, MLPW,  CW, (size_t)CW*MLPW, (size_t)CW*MLPW);

    gemm_a<3,3,float><<<dim3(12,36), 256, 0, stream>>>(y, CW, convT, CW, convb, x, CW, CW);

    for (int l = 0; l < DEPTH; ++l){
        ln_wave<<<NT/4, 256, 0, stream>>>(x, ln1s + l*CW, ln1b + l*CW, y);
        gemm_a<0,2,bf16><<<dim3(36,36), 256, 0, stream>>>(y, CW, wqkvT + (size_t)l*QKVW*CW, CW,
                                                          bqkvA + l*QKVW, qkv, QKVW, CW);
        rope_qk<<<(NT*768)/256, 256, 0, stream>>>(qkv, ropeC);
        vtrans<<<dim3(9, NH, NBATCH), 256, 0, stream>>>(qkv, vT);
        attn_flash<<<dim3(9, NH, NBATCH), 256, 0, stream>>>(qkv, vT, o);
        gemm_a<1,3,float><<<dim3(12,36), 256, 0, stream>>>(o, CW, woT + (size_t)l*CW*CW, CW,
                                                           bo + l*CW, x, CW, CW);
        ln_wave<<<NT/4, 256, 0, stream>>>(x, ln2s + l*CW, ln2b + l*CW, y);
        gemm_a<2,2,bf16><<<dim3(48,36), 256, 0, stream>>>(y, CW, w1T + (size_t)l*CW*MLPW, CW,
                                                          b1 + l*MLPW, h, MLPW, CW);
        gemm_a<1,3,float><<<dim3(12,36), 256, 0, stream>>>(h, MLPW, w2T + (size_t)l*CW*MLPW, MLPW,
                                                           b2 + l*CW, x, CW, MLPW);
    }
    ln_wave<<<NT/4, 256, 0, stream>>>(x, lnfs, lnfb, y);
    mean_kernel<<<dim3(3, NBATCH), 256, 0, stream>>>(y, out);
}

// Round 13
// 991.151 us; speedup vs baseline: 1.0097x; 1.0097x over previous
//
#include <hip/hip_runtime.h>
#include <hip/hip_bf16.h>

typedef __hip_bfloat16 bf16;
typedef __bf16 bf16x8 __attribute__((ext_vector_type(8)));
typedef float f32x4  __attribute__((ext_vector_type(4)));

#define NBATCH 8
#define LTOK   576
#define NT     4608
#define CW     768
#define NH     12
#define HDIM   64
#define DEPTH  4
#define MLPW   3072
#define GRIDP  24
#define IMGS   384
#define QKVW   2304

static __device__ __forceinline__ unsigned bfpair(float a, float b){
    bf16 x = __float2bfloat16(a), y = __float2bfloat16(b);
    return ((unsigned)*(unsigned short*)&y << 16) | *(unsigned short*)&x;
}
static __device__ __forceinline__ float b2f(bf16 v){ return __bfloat162float(v); }

// bijective XCD-aware remap (m204) — row-major chunks
static __device__ __forceinline__ int xcd_swizzle(int orig, int nwg){
    int q = nwg >> 3, r = nwg & 7;
    int xcd = orig & 7, j = orig >> 3;
    int base = (xcd < r) ? xcd*(q+1) : r*(q+1) + (xcd-r)*q;
    return base + j;
}

// async global -> LDS, 16B per lane; LDS dest = wave-uniform base + lane*16
static __device__ __forceinline__ void gl_lds16(const bf16* g, bf16* l){
    __builtin_amdgcn_global_load_lds(
        (const __attribute__((address_space(1))) unsigned int*)(const void*)g,
        (__attribute__((address_space(3))) unsigned int*)(void*)l, 16, 0, 0);
}

// ---------------- RoPE cache ----------------
__global__ void rope_cache_kernel(float* __restrict__ rc){
    int idx = blockIdx.x*256 + threadIdx.x;
    if (idx >= LTOK*16) return;
    int l = idx >> 4, f = idx & 15;
    int py = l / GRIDP, px = l % GRIDP;
    float u = (px + 0.5f) / (float)GRIDP;
    float v = (py + 0.5f) / (float)GRIDP;
    float fr = (float)f / (15.0f + 1e-9f);
    float inv = expf(-fr * 9.210340371976184f);
    float sx, cx, sy, cy;
    sincosf(u * inv, &sx, &cx);
    sincosf(v * inv, &sy, &cy);
    rc[idx]         = cx;
    rc[idx + 9216]  = sx;
    rc[idx + 18432] = cy;
    rc[idx + 27648] = sy;
}

// ---------------- patch gather ----------------
__global__ void patch_gather(const float* __restrict__ img, bf16* __restrict__ p){
    int idx = blockIdx.x*256 + threadIdx.x;
    int t = idx / CW, kk = idx % CW;
    int n = t / LTOK, l = t % LTOK;
    int py = l / GRIDP, px = l % GRIDP;
    int i = kk / 48, r = kk % 48, j = r / 3, c = r % 3;
    p[idx] = __float2bfloat16(img[((size_t)(n*IMGS + py*16 + i)*IMGS + px*16 + j)*3 + c]);
}

// ---------------- batched weight transpose+convert: f32 [K][N] -> bf16 [N][K]
__global__ __launch_bounds__(256) void wtrans_b(const float* __restrict__ in, bf16* __restrict__ out,
                                                int K, int N, size_t inStride, size_t outStride){
    in  += blockIdx.z * inStride;
    out += blockIdx.z * outStride;
    __shared__ float t[32][33];
    const int n0 = blockIdx.x*32, k0 = blockIdx.y*32;
    const int tx = threadIdx.x & 31, ty = threadIdx.x >> 5;
    #pragma unroll
    for (int r = 0; r < 4; ++r)
        t[ty + 8*r][tx] = in[(size_t)(k0 + ty + 8*r)*N + n0 + tx];
    __syncthreads();
    #pragma unroll
    for (int r = 0; r < 4; ++r)
        out[(size_t)(n0 + ty + 8*r)*K + k0 + tx] = __float2bfloat16(t[tx][ty + 8*r]);
}

// ---------------- pack qkv biases ----------------
__global__ void bias_pack(const float* __restrict__ bq, const float* __restrict__ bk,
                          const float* __restrict__ bv, float* __restrict__ o){
    int idx = blockIdx.x*256 + threadIdx.x;    // 4*2304
    int l = idx / QKVW, r = idx % QKVW;
    const float* src = (r < 768) ? (bq + l*768 + r) :
                       (r < 1536) ? (bk + l*768 + r - 768) : (bv + l*768 + r - 1536);
    o[idx] = *src;
}

// fast tanh-gelu: tanh via hardware v_exp_f32 (vs ~25-op libm tanhf)
static __device__ __forceinline__ float gelu_tanh(float x){
    float a = 0.7978845608028654f*(x + 0.044715f*x*x*x);
    float e = __expf(-2.0f*fabsf(a));
    float th = (1.0f - e) / (1.0f + e);
    th = copysignf(th, a);
    return 0.5f*x*(1.0f + th);
}

// ---------------- MFMA GEMM 128x64, BK=64, double-buffered async LDS staging
// with COUNTED vmcnt (T4) — R3 loop structure (best measured).
// XCD mapping: wide grids (>=24 col-tiles) use a 2x4 rectangular per-XCD
// chunk (gridX/2 x gridY/4) so no XCD fetches the whole B panel; narrow
// grids keep row-major chunks. LDS row pitch 64 bf16; chunk c of row r at
// position c^(r&7) (swizzle via permuted GLOBAL source address).
// EPI: 0 = bf16 store, 1 = fp32 residual add, 2 = bf16 gelu, 3 = fp32 store
template<int EPI, typename TC>
__global__ __launch_bounds__(256) void gemm_a(const bf16* __restrict__ A, int lda,
                                              const bf16* __restrict__ B, int ldb,
                                              const float* __restrict__ bias,
                                              TC* __restrict__ C, int ldc, int K){
    __shared__ bf16 As[2][128*64];   // 32 KB
    __shared__ bf16 Bs[2][64*64];    // 16 KB
    const int tid = threadIdx.x;
    const int w = tid >> 6, l = tid & 63;
    const int quad = l >> 4, lr = l & 15;
    const int wm = w & 1, wn = w >> 1;

    const int gx = gridDim.x, gy = gridDim.y;
    const int orig = blockIdx.y * gx + blockIdx.x;
    int tx, ty;
    if (gx >= 24 && (gx & 1) == 0 && (gy & 3) == 0){
        // 2D chunk: XCDs tiled 2 (cols) x 4 (rows)
        const int cw = gx >> 1, ch = gy >> 2;
        const int xcd = orig & 7, j = orig >> 3;
        const int lx = j % cw, ly = j / cw;
        tx = (xcd & 1)*cw + lx;
        ty = (xcd >> 1)*ch + ly;
    } else {
        const int swz = xcd_swizzle(orig, gx*gy);
        tx = swz % gx; ty = swz / gx;
    }
    const int rowT = ty * 128;
    const int colT = tx * 64;

    const int srow = l >> 3;
    const int schk = (l & 7) ^ (srow & 7);

    const bf16* Ap[4];
    const bf16* Bp[2];
    #pragma unroll
    for (int t = 0; t < 4; ++t)
        Ap[t] = A + (size_t)(rowT + (w*4+t)*8 + srow)*lda + schk*8;
    #pragma unroll
    for (int t = 0; t < 2; ++t)
        Bp[t] = B + (size_t)(colT + (w*2+t)*8 + srow)*ldb + schk*8;

    auto STAGE = [&](int k0, int buf){
        #pragma unroll
        for (int t = 0; t < 4; ++t) gl_lds16(Ap[t] + k0, &As[buf][(w*4+t)*512]);
        #pragma unroll
        for (int t = 0; t < 2; ++t) gl_lds16(Bp[t] + k0, &Bs[buf][(w*2+t)*512]);
    };

    f32x4 acc[4][2];
    #pragma unroll
    for (int i = 0; i < 4; ++i)
        #pragma unroll
        for (int j = 0; j < 2; ++j) acc[i][j] = (f32x4){0.f,0.f,0.f,0.f};

    const int S = K >> 6;
    STAGE(0, 0);
    if (S > 1) STAGE(64, 1);

    int cur = 0;
    for (int s = 0; s < S; ++s){
        if (s < S-1) asm volatile("s_waitcnt vmcnt(6)" ::: "memory");
        else         asm volatile("s_waitcnt vmcnt(0)" ::: "memory");
        __builtin_amdgcn_s_barrier();
        #pragma unroll
        for (int kh = 0; kh < 2; ++kh){
            bf16x8 af[4], bfr[2];
            #pragma unroll
            for (int i = 0; i < 4; ++i){
                int r = wm*64 + i*16 + lr;
                af[i] = *(const bf16x8*)(&As[cur][r*64 + (((kh*4 + quad) ^ (r & 7))*8)]);
            }
            #pragma unroll
            for (int j = 0; j < 2; ++j){
                int r = wn*32 + j*16 + lr;
                bfr[j] = *(const bf16x8*)(&Bs[cur][r*64 + (((kh*4 + quad) ^ (r & 7))*8)]);
            }
            #pragma unroll
            for (int i = 0; i < 4; ++i)
                #pragma unroll
                for (int j = 0; j < 2; ++j)
                    acc[i][j] = __builtin_amdgcn_mfma_f32_16x16x32_bf16(af[i], bfr[j], acc[i][j], 0, 0, 0);
        }
        __builtin_amdgcn_s_barrier();
        if (s + 2 < S) STAGE((s + 2)*64, cur);
        cur ^= 1;
    }

    #pragma unroll
    for (int i = 0; i < 4; ++i){
        #pragma unroll
        for (int j = 0; j < 2; ++j){
            const int row = rowT + wm*64 + i*16 + quad*4;
            const int col = colT + wn*32 + j*16 + lr;
            const float bb = bias ? bias[col] : 0.f;
            #pragma unroll
            for (int r = 0; r < 4; ++r){
                float val = acc[i][j][r] + bb;
                TC* cp = C + (size_t)(row + r)*ldc + col;
                if (EPI == 2) val = gelu_tanh(val);
                if (EPI == 1) val += *(float*)cp;
                if (EPI == 0 || EPI == 2) *(bf16*)cp = __float2bfloat16(val);
                else                      *(float*)cp = val;
            }
        }
    }
}

// ---------------- LayerNorm: wave per token ----------------
__global__ __launch_bounds__(256) void ln_wave(const float* __restrict__ x,
                                               const float* __restrict__ sc,
                                               const float* __restrict__ bs,
                                               bf16* __restrict__ y){
    const int tid = threadIdx.x, w = tid >> 6, l = tid & 63;
    const int t = blockIdx.x*4 + w;
    const float4* xr = (const float4*)(x + (size_t)t*CW);
    float4 a[3];
    #pragma unroll
    for (int i = 0; i < 3; ++i) a[i] = xr[l + 64*i];
    float s = 0.f;
    #pragma unroll
    for (int i = 0; i < 3; ++i) s += a[i].x + a[i].y + a[i].z + a[i].w;
    #pragma unroll
    for (int off = 1; off < 64; off <<= 1) s += __shfl_xor(s, off);
    const float m = s * (1.0f/768.0f);
    float vs = 0.f;
    #pragma unroll
    for (int i = 0; i < 3; ++i){
        float dx = a[i].x-m, dy = a[i].y-m, dz = a[i].z-m, dw = a[i].w-m;
        vs += dx*dx + dy*dy + dz*dz + dw*dw;
    }
    #pragma unroll
    for (int off = 1; off < 64; off <<= 1) vs += __shfl_xor(vs, off);
    const float rs = rsqrtf(vs*(1.0f/768.0f) + 1e-6f);
    const float4* scp = (const float4*)sc;
    const float4* bsp = (const float4*)bs;
    uint2* yr = (uint2*)(y + (size_t)t*CW);
    #pragma unroll
    for (int i = 0; i < 3; ++i){
        float4 sv = scp[l + 64*i], bv = bsp[l + 64*i];
        float r0 = (a[i].x-m)*rs*sv.x + bv.x;
        float r1 = (a[i].y-m)*rs*sv.y + bv.y;
        float r2 = (a[i].z-m)*rs*sv.z + bv.z;
        float r3 = (a[i].w-m)*rs*sv.w + bv.w;
        yr[l + 64*i] = make_uint2(bfpair(r0,r1), bfpair(r2,r3));
    }
}

// ---------------- RoPE apply on q and k inside packed qkv ----------------
__global__ void rope_qk(bf16* __restrict__ qkv, const float* __restrict__ rc){
    int idx = blockIdx.x*256 + threadIdx.x;   // NT*768 pairs
    int tok = idx / 768;
    int r = idx % 768;
    int rr, base;
    if (r < 384){ base = 0; rr = r; } else { base = 768; rr = r - 384; }
    int hh = rr >> 5, p = rr & 31;
    int l = tok % LTOK;
    float c, s;
    if (p < 16){ c = rc[l*16 + p];            s = rc[9216 + l*16 + p]; }
    else       { c = rc[18432 + l*16 + p-16]; s = rc[27648 + l*16 + p-16]; }
    bf16* pp = qkv + (size_t)tok*QKVW + base + hh*64 + 2*p;
    unsigned u = *(unsigned*)pp;
    bf16 lo = *(bf16*)&u; unsigned short hi16 = u >> 16; bf16 hi = *(bf16*)&hi16;
    float x = b2f(lo), y = b2f(hi);
    *(unsigned*)pp = bfpair(x*c - y*s, x*s + y*c);
}

// ---------------- V transpose ----------------
__global__ __launch_bounds__(256) void vtrans(const bf16* __restrict__ qkv, bf16* __restrict__ vT){
    __shared__ bf16 tile[64][72];
    const int t0 = blockIdx.x*64, hI = blockIdx.y, nI = blockIdx.z;
    const size_t base = ((size_t)nI*LTOK + t0)*QKVW + 1536 + hI*64;
    const int tid = threadIdx.x;
    #pragma unroll
    for (int i = 0; i < 2; ++i){
        int g = i*256 + tid, r = g >> 3, c = g & 7;
        *(uint4*)&tile[r][c*8] = *(const uint4*)(qkv + base + (size_t)r*QKVW + c*8);
    }
    __syncthreads();
    const size_t obase = ((size_t)(nI*NH + hI)*64)*576 + t0;
    #pragma unroll
    for (int i = 0; i < 2; ++i){
        int g = i*256 + tid, d = g >> 3, c = g & 7;
        bf16 tmp[8];
        #pragma unroll
        for (int j = 0; j < 8; ++j) tmp[j] = tile[c*8 + j][d];
        *(uint4*)(vT + obase + (size_t)d*576 + c*8) = *(uint4*)tmp;
    }
}

// ---------------- Flash attention ----------------
__global__ __launch_bounds__(256) void attn_flash(const bf16* __restrict__ qkv,
                                                  const bf16* __restrict__ vT,
                                                  bf16* __restrict__ o){
    __shared__ bf16 Ks[64*72];
    __shared__ bf16 Vs[64*72];
    __shared__ bf16 Ps[64*72];
    __shared__ float alph[64];
    __shared__ float lsum[64];
    const int tid = threadIdx.x;
    const int w = tid >> 6, l = tid & 63;
    const int quad = l >> 4, lr = l & 15;

    const int nwg = gridDim.x * gridDim.y * gridDim.z;
    const int orig = (blockIdx.z * gridDim.y + blockIdx.y) * gridDim.x + blockIdx.x;
    const int swz = xcd_swizzle(orig, nwg);
    const int q0 = (swz % gridDim.x) * 64;
    const int t2 = swz / gridDim.x;
    const int hI = t2 % gridDim.y;
    const int nI = t2 / gridDim.y;

    const size_t tokBase = (size_t)nI * LTOK;
    const int off = hI * 64;
    const size_t vbase = ((size_t)(nI*NH + hI)*64)*576;

    bf16x8 qf[2];
    #pragma unroll
    for (int kh = 0; kh < 2; ++kh)
        qf[kh] = *(const bf16x8*)(qkv + (tokBase + q0 + w*16 + lr)*QKVW + off + kh*32 + quad*8);

    f32x4 oacc[4];
    #pragma unroll
    for (int j = 0; j < 4; ++j) oacc[j] = (f32x4){0.f,0.f,0.f,0.f};
    float m_run = -3.0e38f, l_run = 0.f;

    for (int ch = 0; ch < 9; ++ch){
        __syncthreads();
        #pragma unroll
        for (int i = 0; i < 2; ++i){
            int g = i*256 + tid, r = g >> 3, c = g & 7;
            *(uint4*)(Ks + r*72 + c*8) =
                *(const uint4*)(qkv + (tokBase + ch*64 + r)*QKVW + 768 + off + c*8);
        }
        #pragma unroll
        for (int i = 0; i < 2; ++i){
            int g = i*256 + tid, d = g >> 3, c = g & 7;
            *(uint4*)(Vs + d*72 + c*8) = *(const uint4*)(vT + vbase + (size_t)d*576 + ch*64 + c*8);
        }
        __syncthreads();

        f32x4 st[4];
        #pragma unroll
        for (int t = 0; t < 4; ++t){
            st[t] = (f32x4){0.f,0.f,0.f,0.f};
            #pragma unroll
            for (int kh = 0; kh < 2; ++kh){
                bf16x8 kf = *(const bf16x8*)(Ks + (t*16 + lr)*72 + kh*32 + quad*8);
                st[t] = __builtin_amdgcn_mfma_f32_16x16x32_bf16(kf, qf[kh], st[t], 0, 0, 0);
            }
        }
        float lm = -3.0e38f;
        #pragma unroll
        for (int t = 0; t < 4; ++t)
            #pragma unroll
            for (int r = 0; r < 4; ++r){
                st[t][r] *= 0.125f;
                lm = fmaxf(lm, st[t][r]);
            }
        lm = fmaxf(lm, __shfl_xor(lm, 16));
        lm = fmaxf(lm, __shfl_xor(lm, 32));
        float mn = fmaxf(m_run, lm);
        float alpha = __expf(m_run - mn);
        m_run = mn;
        float ls = 0.f;
        #pragma unroll
        for (int t = 0; t < 4; ++t)
            #pragma unroll
            for (int r = 0; r < 4; ++r){
                float p = __expf(st[t][r] - mn);
                st[t][r] = p; ls += p;
            }
        ls += __shfl_xor(ls, 16);
        ls += __shfl_xor(ls, 32);
        l_run = l_run*alpha + ls;
        if ((tid & 48) == 0) alph[w*16 + lr] = alpha;
        #pragma unroll
        for (int t = 0; t < 4; ++t)
            #pragma unroll
            for (int r = 0; r < 4; ++r)
                Ps[(w*16 + lr)*72 + t*16 + quad*4 + r] = __float2bfloat16(st[t][r]);
        float af[4];
        #pragma unroll
        for (int r = 0; r < 4; ++r) af[r] = alph[w*16 + quad*4 + r];
        #pragma unroll
        for (int j = 0; j < 4; ++j)
            #pragma unroll
            for (int r = 0; r < 4; ++r) oacc[j][r] *= af[r];
        #pragma unroll
        for (int kh = 0; kh < 2; ++kh){
            bf16x8 pf = *(const bf16x8*)(Ps + (w*16 + lr)*72 + kh*32 + quad*8);
            #pragma unroll
            for (int j = 0; j < 4; ++j){
                bf16x8 vf = *(const bf16x8*)(Vs + (j*16 + lr)*72 + kh*32 + quad*8);
                oacc[j] = __builtin_amdgcn_mfma_f32_16x16x32_bf16(pf, vf, oacc[j], 0, 0, 0);
            }
        }
    }

    if ((tid & 48) == 0) lsum[w*16 + lr] = l_run;
    float linv[4];
    #pragma unroll
    for (int r = 0; r < 4; ++r) linv[r] = 1.0f / lsum[w*16 + quad*4 + r];
    #pragma unroll
    for (int j = 0; j < 4; ++j)
        #pragma unroll
        for (int r = 0; r < 4; ++r)
            o[(tokBase + q0 + w*16 + quad*4 + r)*CW + off + j*16 + lr] =
                __float2bfloat16(oacc[j][r] * linv[r]);
}

// ---------------- final mean ----------------
__global__ void mean_kernel(const bf16* __restrict__ y, float* __restrict__ out){
    int c = blockIdx.x*256 + threadIdx.x;
    int n = blockIdx.y;
    float s = 0.f;
    for (int l = 0; l < LTOK; ++l) s += b2f(y[((size_t)n*LTOK + l)*CW + c]);
    out[n*CW + c] = s * (1.0f/576.0f);
}

extern "C" void kernel_launch(void* const* d_in, const int* in_sizes, int n_in,
                              void* d_out, int out_size, void* d_ws, size_t ws_size,
                              hipStream_t stream){
    const float* image = (const float*)d_in[0];
    const float* convk = (const float*)d_in[1];
    const float* convb = (const float*)d_in[2];
    const float* ln1s  = (const float*)d_in[3];
    const float* ln1b  = (const float*)d_in[4];
    const float* wq    = (const float*)d_in[5];
    const float* bq    = (const float*)d_in[6];
    const float* wk    = (const float*)d_in[7];
    const float* bk    = (const float*)d_in[8];
    const float* wv    = (const float*)d_in[9];
    const float* bv    = (const float*)d_in[10];
    const float* wo    = (const float*)d_in[11];
    const float* bo    = (const float*)d_in[12];
    const float* ln2s  = (const float*)d_in[13];
    const float* ln2b  = (const float*)d_in[14];
    const float* w1    = (const float*)d_in[15];
    const float* b1    = (const float*)d_in[16];
    const float* w2    = (const float*)d_in[17];
    const float* b2    = (const float*)d_in[18];
    const float* lnfs  = (const float*)d_in[19];
    const float* lnfb  = (const float*)d_in[20];
    float* out = (float*)d_out;

    const size_t u = (size_t)NT*CW;
    float* ws    = (float*)d_ws;
    float* ropeC = ws;
    float* bqkvA = ws + 36864;
    float* x     = bqkvA + 4*QKVW;
    bf16*  y     = (bf16*)(x + u);
    bf16*  qkv   = y + u;
    bf16*  o     = qkv + (size_t)NT*QKVW;
    bf16*  h     = o + u;
    bf16*  vT    = h + (size_t)NT*MLPW;
    bf16*  convT = vT + u;
    bf16*  wqkvT = convT + 589824;
    bf16*  woT   = wqkvT + (size_t)4*QKVW*CW;
    bf16*  w1T   = woT + (size_t)4*CW*CW;
    bf16*  w2T   = w1T + (size_t)4*CW*MLPW;

    rope_cache_kernel<<<36, 256, 0, stream>>>(ropeC);
    patch_gather<<<(NT*CW)/256, 256, 0, stream>>>(image, y);
    bias_pack<<<36, 256, 0, stream>>>(bq, bk, bv, bqkvA);
    wtrans_b<<<dim3(24,24,1), 256, 0, stream>>>(convk, convT, CW, CW, 0, 0);
    wtrans_b<<<dim3(24,24,4), 256, 0, stream>>>(wq, wqkvT,           CW, CW, (size_t)CW*CW, (size_t)QKVW*CW);
    wtrans_b<<<dim3(24,24,4), 256, 0, stream>>>(wk, wqkvT + 589824,  CW, CW, (size_t)CW*CW, (size_t)QKVW*CW);
    wtrans_b<<<dim3(24,24,4), 256, 0, stream>>>(wv, wqkvT + 1179648, CW, CW, (size_t)CW*CW, (size_t)QKVW*CW);
    wtrans_b<<<dim3(24,24,4), 256, 0, stream>>>(wo, woT,             CW, CW, (size_t)CW*CW, (size_t)CW*CW);
    wtrans_b<<<dim3(96,24,4), 256, 0, stream>>>(w1, w1T,  CW, MLPW, (size_t)CW*MLPW, (size_t)CW*MLPW);
    wtrans_b<<<dim3(24,96,4), 256, 0, stream>>>(w2, w2T, MLPW,  CW, (size_t)CW*MLPW, (size_t)CW*MLPW);

    gemm_a<3,float><<<dim3(12,36), 256, 0, stream>>>(y, CW, convT, CW, convb, x, CW, CW);

    for (int l = 0; l < DEPTH; ++l){
        ln_wave<<<NT/4, 256, 0, stream>>>(x, ln1s + l*CW, ln1b + l*CW, y);
        gemm_a<0,bf16><<<dim3(36,36), 256, 0, stream>>>(y, CW, wqkvT + (size_t)l*QKVW*CW, CW,
                                                        bqkvA + l*QKVW, qkv, QKVW, CW);
        rope_qk<<<(NT*768)/256, 256, 0, stream>>>(qkv, ropeC);
        vtrans<<<dim3(9, NH, NBATCH), 256, 0, stream>>>(qkv, vT);
        attn_flash<<<dim3(9, NH, NBATCH), 256, 0, stream>>>(qkv, vT, o);
        gemm_a<1,float><<<dim3(12,36), 256, 0, stream>>>(o, CW, woT + (size_t)l*CW*CW, CW,
                                                         bo + l*CW, x, CW, CW);
        ln_wave<<<NT/4, 256, 0, stream>>>(x, ln2s + l*CW, ln2b + l*CW, y);
        gemm_a<2,bf16><<<dim3(48,36), 256, 0, stream>>>(y, CW, w1T + (size_t)l*CW*MLPW, CW,
                                                        b1 + l*MLPW, h, MLPW, CW);
        gemm_a<1,float><<<dim3(12,36), 256, 0, stream>>>(h, MLPW, w2T + (size_t)l*CW*MLPW, MLPW,
                                                         b2 + l*CW, x, CW, MLPW);
    }
    ln_wave<<<NT/4, 256, 0, stream>>>(x, lnfs, lnfb, y);
    mean_kernel<<<dim3(3, NBATCH), 256, 0, stream>>>(y, out);
}

// Round 14
// 950.881 us; speedup vs baseline: 1.0525x; 1.0424x over previous
//
#include <hip/hip_runtime.h>
#include <hip/hip_bf16.h>

typedef __hip_bfloat16 bf16;
typedef __bf16 bf16x8 __attribute__((ext_vector_type(8)));
typedef float f32x4  __attribute__((ext_vector_type(4)));

#define NBATCH 8
#define LTOK   576
#define NT     4608
#define CW     768
#define NH     12
#define HDIM   64
#define DEPTH  4
#define MLPW   3072
#define GRIDP  24
#define IMGS   384
#define QKVW   2304

static __device__ __forceinline__ unsigned bfpair(float a, float b){
    bf16 x = __float2bfloat16(a), y = __float2bfloat16(b);
    return ((unsigned)*(unsigned short*)&y << 16) | *(unsigned short*)&x;
}
static __device__ __forceinline__ float b2f(bf16 v){ return __bfloat162float(v); }

// bijective XCD-aware remap (m204) — row-major chunks
static __device__ __forceinline__ int xcd_swizzle(int orig, int nwg){
    int q = nwg >> 3, r = nwg & 7;
    int xcd = orig & 7, j = orig >> 3;
    int base = (xcd < r) ? xcd*(q+1) : r*(q+1) + (xcd-r)*q;
    return base + j;
}

// async global -> LDS, 16B per lane; LDS dest = wave-uniform base + lane*16
static __device__ __forceinline__ void gl_lds16(const bf16* g, bf16* l){
    __builtin_amdgcn_global_load_lds(
        (const __attribute__((address_space(1))) unsigned int*)(const void*)g,
        (__attribute__((address_space(3))) unsigned int*)(void*)l, 16, 0, 0);
}

// ---------------- RoPE cache ----------------
__global__ void rope_cache_kernel(float* __restrict__ rc){
    int idx = blockIdx.x*256 + threadIdx.x;
    if (idx >= LTOK*16) return;
    int l = idx >> 4, f = idx & 15;
    int py = l / GRIDP, px = l % GRIDP;
    float u = (px + 0.5f) / (float)GRIDP;
    float v = (py + 0.5f) / (float)GRIDP;
    float fr = (float)f / (15.0f + 1e-9f);
    float inv = expf(-fr * 9.210340371976184f);
    float sx, cx, sy, cy;
    sincosf(u * inv, &sx, &cx);
    sincosf(v * inv, &sy, &cy);
    rc[idx]         = cx;
    rc[idx + 9216]  = sx;
    rc[idx + 18432] = cy;
    rc[idx + 27648] = sy;
}

// ---------------- patch gather ----------------
__global__ void patch_gather(const float* __restrict__ img, bf16* __restrict__ p){
    int idx = blockIdx.x*256 + threadIdx.x;
    int t = idx / CW, kk = idx % CW;
    int n = t / LTOK, l = t % LTOK;
    int py = l / GRIDP, px = l % GRIDP;
    int i = kk / 48, r = kk % 48, j = r / 3, c = r % 3;
    p[idx] = __float2bfloat16(img[((size_t)(n*IMGS + py*16 + i)*IMGS + px*16 + j)*3 + c]);
}

// ---------------- batched weight transpose+convert: f32 [K][N] -> bf16 [N][K]
__global__ __launch_bounds__(256) void wtrans_b(const float* __restrict__ in, bf16* __restrict__ out,
                                                int K, int N, size_t inStride, size_t outStride){
    in  += blockIdx.z * inStride;
    out += blockIdx.z * outStride;
    __shared__ float t[32][33];
    const int n0 = blockIdx.x*32, k0 = blockIdx.y*32;
    const int tx = threadIdx.x & 31, ty = threadIdx.x >> 5;
    #pragma unroll
    for (int r = 0; r < 4; ++r)
        t[ty + 8*r][tx] = in[(size_t)(k0 + ty + 8*r)*N + n0 + tx];
    __syncthreads();
    #pragma unroll
    for (int r = 0; r < 4; ++r)
        out[(size_t)(n0 + ty + 8*r)*K + k0 + tx] = __float2bfloat16(t[tx][ty + 8*r]);
}

// ---------------- pack qkv biases ----------------
__global__ void bias_pack(const float* __restrict__ bq, const float* __restrict__ bk,
                          const float* __restrict__ bv, float* __restrict__ o){
    int idx = blockIdx.x*256 + threadIdx.x;    // 4*2304
    int l = idx / QKVW, r = idx % QKVW;
    const float* src = (r < 768) ? (bq + l*768 + r) :
                       (r < 1536) ? (bk + l*768 + r - 768) : (bv + l*768 + r - 1536);
    o[idx] = *src;
}

// fast tanh-gelu: tanh via hardware v_exp_f32 (vs ~25-op libm tanhf)
static __device__ __forceinline__ float gelu_tanh(float x){
    float a = 0.7978845608028654f*(x + 0.044715f*x*x*x);
    float e = __expf(-2.0f*fabsf(a));
    float th = (1.0f - e) / (1.0f + e);
    th = copysignf(th, a);
    return 0.5f*x*(1.0f + th);
}

// ---------------- MFMA GEMM 128x64, BK=64, double-buffered async LDS staging
// with COUNTED vmcnt (T4) — R3 loop structure. Used for qkv (36x36) and
// w1 (48x36): high-block-count grids. 2D per-XCD chunking for wide grids.
// EPI: 0 = bf16 store, 1 = fp32 residual add, 2 = bf16 gelu, 3 = fp32 store
template<int EPI, typename TC>
__global__ __launch_bounds__(256) void gemm_a(const bf16* __restrict__ A, int lda,
                                              const bf16* __restrict__ B, int ldb,
                                              const float* __restrict__ bias,
                                              TC* __restrict__ C, int ldc, int K){
    __shared__ bf16 As[2][128*64];   // 32 KB
    __shared__ bf16 Bs[2][64*64];    // 16 KB
    const int tid = threadIdx.x;
    const int w = tid >> 6, l = tid & 63;
    const int quad = l >> 4, lr = l & 15;
    const int wm = w & 1, wn = w >> 1;

    const int gx = gridDim.x, gy = gridDim.y;
    const int orig = blockIdx.y * gx + blockIdx.x;
    int tx, ty;
    if (gx >= 24 && (gx & 1) == 0 && (gy & 3) == 0){
        // 2D chunk: XCDs tiled 2 (cols) x 4 (rows)
        const int cw = gx >> 1, ch = gy >> 2;
        const int xcd = orig & 7, j = orig >> 3;
        const int lx = j % cw, ly = j / cw;
        tx = (xcd & 1)*cw + lx;
        ty = (xcd >> 1)*ch + ly;
    } else {
        const int swz = xcd_swizzle(orig, gx*gy);
        tx = swz % gx; ty = swz / gx;
    }
    const int rowT = ty * 128;
    const int colT = tx * 64;

    const int srow = l >> 3;
    const int schk = (l & 7) ^ (srow & 7);

    const bf16* Ap[4];
    const bf16* Bp[2];
    #pragma unroll
    for (int t = 0; t < 4; ++t)
        Ap[t] = A + (size_t)(rowT + (w*4+t)*8 + srow)*lda + schk*8;
    #pragma unroll
    for (int t = 0; t < 2; ++t)
        Bp[t] = B + (size_t)(colT + (w*2+t)*8 + srow)*ldb + schk*8;

    auto STAGE = [&](int k0, int buf){
        #pragma unroll
        for (int t = 0; t < 4; ++t) gl_lds16(Ap[t] + k0, &As[buf][(w*4+t)*512]);
        #pragma unroll
        for (int t = 0; t < 2; ++t) gl_lds16(Bp[t] + k0, &Bs[buf][(w*2+t)*512]);
    };

    f32x4 acc[4][2];
    #pragma unroll
    for (int i = 0; i < 4; ++i)
        #pragma unroll
        for (int j = 0; j < 2; ++j) acc[i][j] = (f32x4){0.f,0.f,0.f,0.f};

    const int S = K >> 6;
    STAGE(0, 0);
    if (S > 1) STAGE(64, 1);

    int cur = 0;
    for (int s = 0; s < S; ++s){
        if (s < S-1) asm volatile("s_waitcnt vmcnt(6)" ::: "memory");
        else         asm volatile("s_waitcnt vmcnt(0)" ::: "memory");
        __builtin_amdgcn_s_barrier();
        #pragma unroll
        for (int kh = 0; kh < 2; ++kh){
            bf16x8 af[4], bfr[2];
            #pragma unroll
            for (int i = 0; i < 4; ++i){
                int r = wm*64 + i*16 + lr;
                af[i] = *(const bf16x8*)(&As[cur][r*64 + (((kh*4 + quad) ^ (r & 7))*8)]);
            }
            #pragma unroll
            for (int j = 0; j < 2; ++j){
                int r = wn*32 + j*16 + lr;
                bfr[j] = *(const bf16x8*)(&Bs[cur][r*64 + (((kh*4 + quad) ^ (r & 7))*8)]);
            }
            #pragma unroll
            for (int i = 0; i < 4; ++i)
                #pragma unroll
                for (int j = 0; j < 2; ++j)
                    acc[i][j] = __builtin_amdgcn_mfma_f32_16x16x32_bf16(af[i], bfr[j], acc[i][j], 0, 0, 0);
        }
        __builtin_amdgcn_s_barrier();
        if (s + 2 < S) STAGE((s + 2)*64, cur);
        cur ^= 1;
    }

    #pragma unroll
    for (int i = 0; i < 4; ++i){
        #pragma unroll
        for (int j = 0; j < 2; ++j){
            const int row = rowT + wm*64 + i*16 + quad*4;
            const int col = colT + wn*32 + j*16 + lr;
            const float bb = bias ? bias[col] : 0.f;
            #pragma unroll
            for (int r = 0; r < 4; ++r){
                float val = acc[i][j][r] + bb;
                TC* cp = C + (size_t)(row + r)*ldc + col;
                if (EPI == 2) val = gelu_tanh(val);
                if (EPI == 1) val += *(float*)cp;
                if (EPI == 0 || EPI == 2) *(bf16*)cp = __float2bfloat16(val);
                else                      *(float*)cp = val;
            }
        }
    }
}

// ---------------- MFMA GEMM 64x64 ("small"), BK=64, 4 waves 2x2 (32x32/wave)
// for the LATENCY-BOUND narrow GEMMs (conv/wo/w2: N=768): grid 12x72 = 864
// blocks (3.4/CU, 2x the 128x64 tiling) at 32 KB LDS (5 blocks/CU capacity)
// -> doubles waves/CU with no extra HBM traffic. Counted vmcnt(4) (4 loads/
// wave/STAGE). Same swizzle scheme as gemm_a.
template<int EPI, typename TC>
__global__ __launch_bounds__(256) void gemm_s(const bf16* __restrict__ A, int lda,
                                              const bf16* __restrict__ B, int ldb,
                                              const float* __restrict__ bias,
                                              TC* __restrict__ C, int ldc, int K){
    __shared__ bf16 As[2][64*64];    // 16 KB
    __shared__ bf16 Bs[2][64*64];    // 16 KB
    const int tid = threadIdx.x;
    const int w = tid >> 6, l = tid & 63;
    const int quad = l >> 4, lr = l & 15;
    const int wm = w & 1, wn = w >> 1;

    const int swz = xcd_swizzle(blockIdx.y * gridDim.x + blockIdx.x, gridDim.x * gridDim.y);
    const int rowT = (swz / gridDim.x) * 64;
    const int colT = (swz % gridDim.x) * 64;

    const int srow = l >> 3;
    const int schk = (l & 7) ^ (srow & 7);

    const bf16* Ap[2];
    const bf16* Bp[2];
    #pragma unroll
    for (int t = 0; t < 2; ++t)
        Ap[t] = A + (size_t)(rowT + (w*2+t)*8 + srow)*lda + schk*8;
    #pragma unroll
    for (int t = 0; t < 2; ++t)
        Bp[t] = B + (size_t)(colT + (w*2+t)*8 + srow)*ldb + schk*8;

    auto STAGE = [&](int k0, int buf){
        #pragma unroll
        for (int t = 0; t < 2; ++t) gl_lds16(Ap[t] + k0, &As[buf][(w*2+t)*512]);
        #pragma unroll
        for (int t = 0; t < 2; ++t) gl_lds16(Bp[t] + k0, &Bs[buf][(w*2+t)*512]);
    };

    f32x4 acc[2][2];
    #pragma unroll
    for (int i = 0; i < 2; ++i)
        #pragma unroll
        for (int j = 0; j < 2; ++j) acc[i][j] = (f32x4){0.f,0.f,0.f,0.f};

    const int S = K >> 6;
    STAGE(0, 0);
    if (S > 1) STAGE(64, 1);

    int cur = 0;
    for (int s = 0; s < S; ++s){
        if (s < S-1) asm volatile("s_waitcnt vmcnt(4)" ::: "memory");
        else         asm volatile("s_waitcnt vmcnt(0)" ::: "memory");
        __builtin_amdgcn_s_barrier();
        #pragma unroll
        for (int kh = 0; kh < 2; ++kh){
            bf16x8 af[2], bfr[2];
            #pragma unroll
            for (int i = 0; i < 2; ++i){
                int r = wm*32 + i*16 + lr;
                af[i] = *(const bf16x8*)(&As[cur][r*64 + (((kh*4 + quad) ^ (r & 7))*8)]);
            }
            #pragma unroll
            for (int j = 0; j < 2; ++j){
                int r = wn*32 + j*16 + lr;
                bfr[j] = *(const bf16x8*)(&Bs[cur][r*64 + (((kh*4 + quad) ^ (r & 7))*8)]);
            }
            #pragma unroll
            for (int i = 0; i < 2; ++i)
                #pragma unroll
                for (int j = 0; j < 2; ++j)
                    acc[i][j] = __builtin_amdgcn_mfma_f32_16x16x32_bf16(af[i], bfr[j], acc[i][j], 0, 0, 0);
        }
        __builtin_amdgcn_s_barrier();
        if (s + 2 < S) STAGE((s + 2)*64, cur);
        cur ^= 1;
    }

    #pragma unroll
    for (int i = 0; i < 2; ++i){
        #pragma unroll
        for (int j = 0; j < 2; ++j){
            const int row = rowT + wm*32 + i*16 + quad*4;
            const int col = colT + wn*32 + j*16 + lr;
            const float bb = bias ? bias[col] : 0.f;
            #pragma unroll
            for (int r = 0; r < 4; ++r){
                float val = acc[i][j][r] + bb;
                TC* cp = C + (size_t)(row + r)*ldc + col;
                if (EPI == 2) val = gelu_tanh(val);
                if (EPI == 1) val += *(float*)cp;
                if (EPI == 0 || EPI == 2) *(bf16*)cp = __float2bfloat16(val);
                else                      *(float*)cp = val;
            }
        }
    }
}

// ---------------- LayerNorm: wave per token ----------------
__global__ __launch_bounds__(256) void ln_wave(const float* __restrict__ x,
                                               const float* __restrict__ sc,
                                               const float* __restrict__ bs,
                                               bf16* __restrict__ y){
    const int tid = threadIdx.x, w = tid >> 6, l = tid & 63;
    const int t = blockIdx.x*4 + w;
    const float4* xr = (const float4*)(x + (size_t)t*CW);
    float4 a[3];
    #pragma unroll
    for (int i = 0; i < 3; ++i) a[i] = xr[l + 64*i];
    float s = 0.f;
    #pragma unroll
    for (int i = 0; i < 3; ++i) s += a[i].x + a[i].y + a[i].z + a[i].w;
    #pragma unroll
    for (int off = 1; off < 64; off <<= 1) s += __shfl_xor(s, off);
    const float m = s * (1.0f/768.0f);
    float vs = 0.f;
    #pragma unroll
    for (int i = 0; i < 3; ++i){
        float dx = a[i].x-m, dy = a[i].y-m, dz = a[i].z-m, dw = a[i].w-m;
        vs += dx*dx + dy*dy + dz*dz + dw*dw;
    }
    #pragma unroll
    for (int off = 1; off < 64; off <<= 1) vs += __shfl_xor(vs, off);
    const float rs = rsqrtf(vs*(1.0f/768.0f) + 1e-6f);
    const float4* scp = (const float4*)sc;
    const float4* bsp = (const float4*)bs;
    uint2* yr = (uint2*)(y + (size_t)t*CW);
    #pragma unroll
    for (int i = 0; i < 3; ++i){
        float4 sv = scp[l + 64*i], bv = bsp[l + 64*i];
        float r0 = (a[i].x-m)*rs*sv.x + bv.x;
        float r1 = (a[i].y-m)*rs*sv.y + bv.y;
        float r2 = (a[i].z-m)*rs*sv.z + bv.z;
        float r3 = (a[i].w-m)*rs*sv.w + bv.w;
        yr[l + 64*i] = make_uint2(bfpair(r0,r1), bfpair(r2,r3));
    }
}

// ---------------- RoPE apply on q and k inside packed qkv ----------------
__global__ void rope_qk(bf16* __restrict__ qkv, const float* __restrict__ rc){
    int idx = blockIdx.x*256 + threadIdx.x;   // NT*768 pairs
    int tok = idx / 768;
    int r = idx % 768;
    int rr, base;
    if (r < 384){ base = 0; rr = r; } else { base = 768; rr = r - 384; }
    int hh = rr >> 5, p = rr & 31;
    int l = tok % LTOK;
    float c, s;
    if (p < 16){ c = rc[l*16 + p];            s = rc[9216 + l*16 + p]; }
    else       { c = rc[18432 + l*16 + p-16]; s = rc[27648 + l*16 + p-16]; }
    bf16* pp = qkv + (size_t)tok*QKVW + base + hh*64 + 2*p;
    unsigned u = *(unsigned*)pp;
    bf16 lo = *(bf16*)&u; unsigned short hi16 = u >> 16; bf16 hi = *(bf16*)&hi16;
    float x = b2f(lo), y = b2f(hi);
    *(unsigned*)pp = bfpair(x*c - y*s, x*s + y*c);
}

// ---------------- V transpose ----------------
__global__ __launch_bounds__(256) void vtrans(const bf16* __restrict__ qkv, bf16* __restrict__ vT){
    __shared__ bf16 tile[64][72];
    const int t0 = blockIdx.x*64, hI = blockIdx.y, nI = blockIdx.z;
    const size_t base = ((size_t)nI*LTOK + t0)*QKVW + 1536 + hI*64;
    const int tid = threadIdx.x;
    #pragma unroll
    for (int i = 0; i < 2; ++i){
        int g = i*256 + tid, r = g >> 3, c = g & 7;
        *(uint4*)&tile[r][c*8] = *(const uint4*)(qkv + base + (size_t)r*QKVW + c*8);
    }
    __syncthreads();
    const size_t obase = ((size_t)(nI*NH + hI)*64)*576 + t0;
    #pragma unroll
    for (int i = 0; i < 2; ++i){
        int g = i*256 + tid, d = g >> 3, c = g & 7;
        bf16 tmp[8];
        #pragma unroll
        for (int j = 0; j < 8; ++j) tmp[j] = tile[c*8 + j][d];
        *(uint4*)(vT + obase + (size_t)d*576 + c*8) = *(uint4*)tmp;
    }
}

// ---------------- Flash attention ----------------
__global__ __launch_bounds__(256) void attn_flash(const bf16* __restrict__ qkv,
                                                  const bf16* __restrict__ vT,
                                                  bf16* __restrict__ o){
    __shared__ bf16 Ks[64*72];
    __shared__ bf16 Vs[64*72];
    __shared__ bf16 Ps[64*72];
    __shared__ float alph[64];
    __shared__ float lsum[64];
    const int tid = threadIdx.x;
    const int w = tid >> 6, l = tid & 63;
    const int quad = l >> 4, lr = l & 15;

    const int nwg = gridDim.x * gridDim.y * gridDim.z;
    const int orig = (blockIdx.z * gridDim.y + blockIdx.y) * gridDim.x + blockIdx.x;
    const int swz = xcd_swizzle(orig, nwg);
    const int q0 = (swz % gridDim.x) * 64;
    const int t2 = swz / gridDim.x;
    const int hI = t2 % gridDim.y;
    const int nI = t2 / gridDim.y;

    const size_t tokBase = (size_t)nI * LTOK;
    const int off = hI * 64;
    const size_t vbase = ((size_t)(nI*NH + hI)*64)*576;

    bf16x8 qf[2];
    #pragma unroll
    for (int kh = 0; kh < 2; ++kh)
        qf[kh] = *(const bf16x8*)(qkv + (tokBase + q0 + w*16 + lr)*QKVW + off + kh*32 + quad*8);

    f32x4 oacc[4];
    #pragma unroll
    for (int j = 0; j < 4; ++j) oacc[j] = (f32x4){0.f,0.f,0.f,0.f};
    float m_run = -3.0e38f, l_run = 0.f;

    for (int ch = 0; ch < 9; ++ch){
        __syncthreads();
        #pragma unroll
        for (int i = 0; i < 2; ++i){
            int g = i*256 + tid, r = g >> 3, c = g & 7;
            *(uint4*)(Ks + r*72 + c*8) =
                *(const uint4*)(qkv + (tokBase + ch*64 + r)*QKVW + 768 + off + c*8);
        }
        #pragma unroll
        for (int i = 0; i < 2; ++i){
            int g = i*256 + tid, d = g >> 3, c = g & 7;
            *(uint4*)(Vs + d*72 + c*8) = *(const uint4*)(vT + vbase + (size_t)d*576 + ch*64 + c*8);
        }
        __syncthreads();

        f32x4 st[4];
        #pragma unroll
        for (int t = 0; t < 4; ++t){
            st[t] = (f32x4){0.f,0.f,0.f,0.f};
            #pragma unroll
            for (int kh = 0; kh < 2; ++kh){
                bf16x8 kf = *(const bf16x8*)(Ks + (t*16 + lr)*72 + kh*32 + quad*8);
                st[t] = __builtin_amdgcn_mfma_f32_16x16x32_bf16(kf, qf[kh], st[t], 0, 0, 0);
            }
        }
        float lm = -3.0e38f;
        #pragma unroll
        for (int t = 0; t < 4; ++t)
            #pragma unroll
            for (int r = 0; r < 4; ++r){
                st[t][r] *= 0.125f;
                lm = fmaxf(lm, st[t][r]);
            }
        lm = fmaxf(lm, __shfl_xor(lm, 16));
        lm = fmaxf(lm, __shfl_xor(lm, 32));
        float mn = fmaxf(m_run, lm);
        float alpha = __expf(m_run - mn);
        m_run = mn;
        float ls = 0.f;
        #pragma unroll
        for (int t = 0; t < 4; ++t)
            #pragma unroll
            for (int r = 0; r < 4; ++r){
                float p = __expf(st[t][r] - mn);
                st[t][r] = p; ls += p;
            }
        ls += __shfl_xor(ls, 16);
        ls += __shfl_xor(ls, 32);
        l_run = l_run*alpha + ls;
        if ((tid & 48) == 0) alph[w*16 + lr] = alpha;
        #pragma unroll
        for (int t = 0; t < 4; ++t)
            #pragma unroll
            for (int r = 0; r < 4; ++r)
                Ps[(w*16 + lr)*72 + t*16 + quad*4 + r] = __float2bfloat16(st[t][r]);
        float af[4];
        #pragma unroll
        for (int r = 0; r < 4; ++r) af[r] = alph[w*16 + quad*4 + r];
        #pragma unroll
        for (int j = 0; j < 4; ++j)
            #pragma unroll
            for (int r = 0; r < 4; ++r) oacc[j][r] *= af[r];
        #pragma unroll
        for (int kh = 0; kh < 2; ++kh){
            bf16x8 pf = *(const bf16x8*)(Ps + (w*16 + lr)*72 + kh*32 + quad*8);
            #pragma unroll
            for (int j = 0; j < 4; ++j){
                bf16x8 vf = *(const bf16x8*)(Vs + (j*16 + lr)*72 + kh*32 + quad*8);
                oacc[j] = __builtin_amdgcn_mfma_f32_16x16x32_bf16(pf, vf, oacc[j], 0, 0, 0);
            }
        }
    }

    if ((tid & 48) == 0) lsum[w*16 + lr] = l_run;
    float linv[4];
    #pragma unroll
    for (int r = 0; r < 4; ++r) linv[r] = 1.0f / lsum[w*16 + quad*4 + r];
    #pragma unroll
    for (int j = 0; j < 4; ++j)
        #pragma unroll
        for (int r = 0; r < 4; ++r)
            o[(tokBase + q0 + w*16 + quad*4 + r)*CW + off + j*16 + lr] =
                __float2bfloat16(oacc[j][r] * linv[r]);
}

// ---------------- final mean ----------------
__global__ void mean_kernel(const bf16* __restrict__ y, float* __restrict__ out){
    int c = blockIdx.x*256 + threadIdx.x;
    int n = blockIdx.y;
    float s = 0.f;
    for (int l = 0; l < LTOK; ++l) s += b2f(y[((size_t)n*LTOK + l)*CW + c]);
    out[n*CW + c] = s * (1.0f/576.0f);
}

extern "C" void kernel_launch(void* const* d_in, const int* in_sizes, int n_in,
                              void* d_out, int out_size, void* d_ws, size_t ws_size,
                              hipStream_t stream){
    const float* image = (const float*)d_in[0];
    const float* convk = (const float*)d_in[1];
    const float* convb = (const float*)d_in[2];
    const float* ln1s  = (const float*)d_in[3];
    const float* ln1b  = (const float*)d_in[4];
    const float* wq    = (const float*)d_in[5];
    const float* bq    = (const float*)d_in[6];
    const float* wk    = (const float*)d_in[7];
    const float* bk    = (const float*)d_in[8];
    const float* wv    = (const float*)d_in[9];
    const float* bv    = (const float*)d_in[10];
    const float* wo    = (const float*)d_in[11];
    const float* bo    = (const float*)d_in[12];
    const float* ln2s  = (const float*)d_in[13];
    const float* ln2b  = (const float*)d_in[14];
    const float* w1    = (const float*)d_in[15];
    const float* b1    = (const float*)d_in[16];
    const float* w2    = (const float*)d_in[17];
    const float* b2    = (const float*)d_in[18];
    const float* lnfs  = (const float*)d_in[19];
    const float* lnfb  = (const float*)d_in[20];
    float* out = (float*)d_out;

    const size_t u = (size_t)NT*CW;
    float* ws    = (float*)d_ws;
    float* ropeC = ws;
    float* bqkvA = ws + 36864;
    float* x     = bqkvA + 4*QKVW;
    bf16*  y     = (bf16*)(x + u);
    bf16*  qkv   = y + u;
    bf16*  o     = qkv + (size_t)NT*QKVW;
    bf16*  h     = o + u;
    bf16*  vT    = h + (size_t)NT*MLPW;
    bf16*  convT = vT + u;
    bf16*  wqkvT = convT + 589824;
    bf16*  woT   = wqkvT + (size_t)4*QKVW*CW;
    bf16*  w1T   = woT + (size_t)4*CW*CW;
    bf16*  w2T   = w1T + (size_t)4*CW*MLPW;

    rope_cache_kernel<<<36, 256, 0, stream>>>(ropeC);
    patch_gather<<<(NT*CW)/256, 256, 0, stream>>>(image, y);
    bias_pack<<<36, 256, 0, stream>>>(bq, bk, bv, bqkvA);
    wtrans_b<<<dim3(24,24,1), 256, 0, stream>>>(convk, convT, CW, CW, 0, 0);
    wtrans_b<<<dim3(24,24,4), 256, 0, stream>>>(wq, wqkvT,           CW, CW, (size_t)CW*CW, (size_t)QKVW*CW);
    wtrans_b<<<dim3(24,24,4), 256, 0, stream>>>(wk, wqkvT + 589824,  CW, CW, (size_t)CW*CW, (size_t)QKVW*CW);
    wtrans_b<<<dim3(24,24,4), 256, 0, stream>>>(wv, wqkvT + 1179648, CW, CW, (size_t)CW*CW, (size_t)QKVW*CW);
    wtrans_b<<<dim3(24,24,4), 256, 0, stream>>>(wo, woT,             CW, CW, (size_t)CW*CW, (size_t)CW*CW);
    wtrans_b<<<dim3(96,24,4), 256, 0, stream>>>(w1, w1T,  CW, MLPW, (size_t)CW*MLPW, (size_t)CW*MLPW);
    wtrans_b<<<dim3(24,96,4), 256, 0, stream>>>(w2, w2T, MLPW,  CW, (size_t)CW*MLPW, (size_t)CW*MLPW);

    gemm_s<3,float><<<dim3(12,72), 256, 0, stream>>>(y, CW, convT, CW, convb, x, CW, CW);

    for (int l = 0; l < DEPTH; ++l){
        ln_wave<<<NT/4, 256, 0, stream>>>(x, ln1s + l*CW, ln1b + l*CW, y);
        gemm_a<0,bf16><<<dim3(36,36), 256, 0, stream>>>(y, CW, wqkvT + (size_t)l*QKVW*CW, CW,
                                                        bqkvA + l*QKVW, qkv, QKVW, CW);
        rope_qk<<<(NT*768)/256, 256, 0, stream>>>(qkv, ropeC);
        vtrans<<<dim3(9, NH, NBATCH), 256, 0, stream>>>(qkv, vT);
        attn_flash<<<dim3(9, NH, NBATCH), 256, 0, stream>>>(qkv, vT, o);
        gemm_s<1,float><<<dim3(12,72), 256, 0, stream>>>(o, CW, woT + (size_t)l*CW*CW, CW,
                                                         bo + l*CW, x, CW, CW);
        ln_wave<<<NT/4, 256, 0, stream>>>(x, ln2s + l*CW, ln2b + l*CW, y);
        gemm_a<2,bf16><<<dim3(48,36), 256, 0, stream>>>(y, CW, w1T + (size_t)l*CW*MLPW, CW,
                                                        b1 + l*MLPW, h, MLPW, CW);
        gemm_s<1,float><<<dim3(12,72), 256, 0, stream>>>(h, MLPW, w2T + (size_t)l*CW*MLPW, MLPW,
                                                         b2 + l*CW, x, CW, MLPW);
    }
    ln_wave<<<NT/4, 256, 0, stream>>>(x, lnfs, lnfb, y);
    mean_kernel<<<dim3(3, NBATCH), 256, 0, stream>>>(y, out);
}